// Round 4
// baseline (280.682 us; speedup 1.0000x reference)
//
#include <hip/hip_runtime.h>

#define B_ 16
#define C_ 3
#define H_ 384
#define W_ 1280
#define HW_ (H_*W_)
#define EPS_ 1e-7f

// R0-R3 lesson: duration pinned ~110us across 2.5x HBM-traffic changes, wave
// count changes, scheduling changes. The invariant = 10 VMEM/px (6 divergent
// 8B gathers). Theory: TA processes divergent gathers ~1 lane-address/cycle
// -> ~64 cyc per gather instruction; kernel is VMEM-address-bound.
// This version: horizontal pixel pairing. dpx/dj = m00 ~ 1, so both pixels'
// 4 x-taps fit one 16B window -> ONE dwordx4 gather per (row,channel) serves
// 2 pixels: 3 divergent addresses/px instead of 6.
#define COLS_ 256
#define ROWS_ 2
#define BANDS_ (W_/COLS_)              // 5
#define RTILES_ (H_/ROWS_)             // 192
#define NBLK_ (BANDS_*RTILES_*B_)      // 15360 (div by 8 -> swizzle bijective)
#define NXCD_ 8

typedef float v2f __attribute__((ext_vector_type(2)));
typedef float v4f __attribute__((ext_vector_type(4)));

// 8/16-byte loads at 4-byte alignment — gfx950 global loads support this.
__device__ __forceinline__ v2f load2(const float* p) {
  v2f r; __builtin_memcpy(&r, p, 8); return r;
}
__device__ __forceinline__ v4f load4(const float* p) {
  v4f r; __builtin_memcpy(&r, p, 16); return r;
}
__device__ __forceinline__ void storent2(float* p, float a, float b) {
  v2f r; r.x = a; r.y = b;
  __builtin_nontemporal_store(r, (v2f*)p);   // p is 8B-aligned (even col, even W)
}
__device__ __forceinline__ float dot4(v4f a, v4f b) {
  return a.x*b.x + a.y*b.y + a.z*b.z + a.w*b.w;
}

__device__ __forceinline__ void mat3mul(const float* A, const float* Bm, float* C) {
  #pragma unroll
  for (int i = 0; i < 3; i++)
    #pragma unroll
    for (int j = 0; j < 3; j++)
      C[i*3+j] = A[i*3+0]*Bm[0*3+j] + A[i*3+1]*Bm[1*3+j] + A[i*3+2]*Bm[2*3+j];
}

// M = K * R * inv(K), T = K * t for batch b.
__device__ void compute_MT(const float* __restrict__ pose,
                           const float* __restrict__ intr,
                           int b, float* M, float* T)
{
  float K[9];
  #pragma unroll
  for (int i = 0; i < 9; i++) K[i] = intr[b*9 + i];
  float aa0 = pose[b*6 + 0], aa1 = pose[b*6 + 1], aa2 = pose[b*6 + 2];
  float t0  = pose[b*6 + 3], t1  = pose[b*6 + 4], t2  = pose[b*6 + 5];

  float theta = sqrtf(aa0*aa0 + aa1*aa1 + aa2*aa2);
  float invn  = 1.0f / (theta + EPS_);
  float x = aa0*invn, y = aa1*invn, z = aa2*invn;
  float c = cosf(theta), s = sinf(theta), t = 1.0f - c;
  float R[9] = {
    t*x*x + c,   t*x*y - s*z, t*z*x + s*y,
    t*x*y + s*z, t*y*y + c,   t*y*z - s*x,
    t*z*x - s*y, t*y*z + s*x, t*z*z + c
  };

  float a = K[0], bb = K[1], cc = K[2];
  float d = K[3], e  = K[4], f  = K[5];
  float g = K[6], h  = K[7], ii = K[8];
  float A0 = e*ii - f*h, A1 = f*g - d*ii, A2 = d*h - e*g;
  float id = 1.0f / (a*A0 + bb*A1 + cc*A2);
  float iK[9] = {
    A0*id, (cc*h - bb*ii)*id, (bb*f - cc*e)*id,
    A1*id, (a*ii - cc*g)*id,  (cc*d - a*f)*id,
    A2*id, (bb*g - a*h)*id,   (a*e  - bb*d)*id
  };

  float KR[9];
  mat3mul(K, R, KR);
  mat3mul(KR, iK, M);
  T[0] = K[0]*t0 + K[1]*t1 + K[2]*t2;
  T[1] = K[3]*t0 + K[4]*t1 + K[5]*t2;
  T[2] = K[6]*t0 + K[7]*t1 + K[8]*t2;
}

// Project one pixel -> masked bilinear weights + clamped tap indices.
__device__ __forceinline__ void project_px(
    float xf, float yf, float d,
    float m00,float m01,float m02,float m10,float m11,float m12,
    float m20,float m21,float m22,float T0,float T1,float T2,
    float& wx0,float& wx1,float& wy0,float& wy1,
    int& xc0,int& xc1,int& yc0,int& yc1)
{
  float cz = (m20*xf + m21*yf + m22)*d + T2;
  float inv = 1.0f / (cz + EPS_);
  float px = ((m00*xf + m01*yf + m02)*d + T0) * inv;
  float py = ((m10*xf + m11*yf + m12)*d + T1) * inv;
  float x0f = floorf(px), y0f = floorf(py);
  float fx1 = px - x0f, fx0 = 1.0f - fx1;
  float fy1 = py - y0f, fy0 = 1.0f - fy1;
  float mx0 = (x0f >= 0.0f && x0f <= (float)(W_-1)) ? 1.0f : 0.0f;
  float mx1 = (x0f+1.0f >= 0.0f && x0f+1.0f <= (float)(W_-1)) ? 1.0f : 0.0f;
  float my0 = (y0f >= 0.0f && y0f <= (float)(H_-1)) ? 1.0f : 0.0f;
  float my1 = (y0f+1.0f >= 0.0f && y0f+1.0f <= (float)(H_-1)) ? 1.0f : 0.0f;
  wx0 = fx0*mx0; wx1 = fx1*mx1;     // x-masks folded into x-weights
  wy0 = fy0*my0; wy1 = fy1*my1;     // y-masks folded into y-weights
  xc0 = (int)fminf(fmaxf(x0f, 0.0f), (float)(W_-1));
  xc1 = (int)fminf(fmaxf(x0f+1.0f, 0.0f), (float)(W_-1));
  yc0 = (int)fminf(fmaxf(y0f, 0.0f), (float)(H_-1));
  yc1 = (int)fminf(fmaxf(y0f+1.0f, 0.0f), (float)(H_-1));
}

__global__ __launch_bounds__(256) void warp_kernel(
    const float* __restrict__ src,
    const float* __restrict__ depth,
    const float* __restrict__ pose,
    const float* __restrict__ intr,
    float* __restrict__ out)
{
  __shared__ float sp[12];

  // XCD-aware bijective swizzle (R1: cut FETCH 284->57 MB; keep).
  int l = blockIdx.x;
  int w = (l & (NXCD_-1)) * (NBLK_/NXCD_) + (l >> 3);
  int rt   = w % RTILES_;
  int tmp  = w / RTILES_;
  int band = tmp % BANDS_;
  int b    = tmp / BANDS_;

  // Block tile: 256 cols x 2 rows. Thread t -> row (t>>7), column-pair (t&127).
  int t  = threadIdx.x;
  int cp = t & 127;
  int rr = t >> 7;
  int j0 = band * COLS_ + 2*cp;      // even column, pixels A=(i,j0), B=(i,j0+1)
  int i  = rt * ROWS_ + rr;

  // Coalesced dwordx2 depth load issued before the barrier.
  const float* dpp = depth + (size_t)b * HW_ + (size_t)i * W_ + j0;
  v2f dpair = load2(dpp);

  if (t == 0) {
    float M[9], T[3];
    compute_MT(pose, intr, b, M, T);
    #pragma unroll
    for (int k = 0; k < 9; k++) sp[k] = M[k];
    #pragma unroll
    for (int k = 0; k < 3; k++) sp[9 + k] = T[k];
  }
  __syncthreads();
  float m00 = sp[0], m01 = sp[1], m02 = sp[2];
  float m10 = sp[3], m11 = sp[4], m12 = sp[5];
  float m20 = sp[6], m21 = sp[7], m22 = sp[8];
  float T0  = sp[9], T1  = sp[10], T2 = sp[11];

  float yf = (float)i;

  // Per-pixel projection + weights.
  float wxA0,wxA1,wyA0,wyA1, wxB0,wxB1,wyB0,wyB1;
  int xcA0,xcA1,ycA0,ycA1, xcB0,xcB1,ycB0,ycB1;
  project_px((float)j0,     yf, dpair.x, m00,m01,m02,m10,m11,m12,m20,m21,m22,T0,T1,T2,
             wxA0,wxA1,wyA0,wyA1, xcA0,xcA1,ycA0,ycA1);
  project_px((float)(j0+1), yf, dpair.y, m00,m01,m02,m10,m11,m12,m20,m21,m22,T0,T1,T2,
             wxB0,wxB1,wyB0,wyB1, xcB0,xcB1,ycB0,ycB1);

  // ---- Shared 4-wide x-window [bp, bp+3]. A's taps always land in [0,3];
  // B's do whenever pxB-pxA < 2 (true for all realistic poses; else fallback).
  int baseA = xcA0 < (W_-2) ? xcA0 : (W_-2);
  int bp    = baseA < (W_-4) ? baseA : (W_-4);
  int pA0 = xcA0 - bp, pA1 = xcA1 - bp;    // in [0,3] by construction
  int pB0 = xcB0 - bp, pB1 = xcB1 - bp;    // expected [0,3]

  // ---- Row slots: R0=ycA0, R1=ycA1 (one dwordx4 each). B's rows map onto
  // {R0, R1} or, when the pair straddles a row boundary, one extra row E.
  int R0 = ycA0, R1 = ycA1;
  int sB0 = (ycB0 == R0) ? 0 : ((ycB0 == R1) ? 1 : 2);
  int sB1 = (ycB1 == R1) ? 1 : ((ycB1 == R0) ? 0 : 2);
  bool needE = (sB0 == 2) || (sB1 == 2);
  bool fb = (pB1 > 3) || (pB0 < 0) || ((sB0 == 2) && (sB1 == 2));
  int yE = (sB0 == 2) ? ycB0 : ycB1;

  // B row-weight one-hot over {R0, R1, E}.
  float u0 = (sB0 == 0 ? wyB0 : 0.0f) + (sB1 == 0 ? wyB1 : 0.0f);
  float u1 = (sB0 == 1 ? wyB0 : 0.0f) + (sB1 == 1 ? wyB1 : 0.0f);
  float u2 = (sB0 == 2 ? wyB0 : 0.0f) + (sB1 == 2 ? wyB1 : 0.0f);

  // 4-wide weight vectors, pre-scaled by row weights; shared by all 3 channels.
  // (k is compile-time after unroll -> stays in registers, no scratch.)
  v4f wA0v, wA1v, wB0v, wB1v, wB2v;
  #pragma unroll
  for (int k = 0; k < 4; k++) {
    float wva = (pA0 == k ? wxA0 : 0.0f) + (pA1 == k ? wxA1 : 0.0f);
    float wvb = (pB0 == k ? wxB0 : 0.0f) + (pB1 == k ? wxB1 : 0.0f);
    wA0v[k] = wva * wyA0;
    wA1v[k] = wva * wyA1;
    wB0v[k] = wvb * u0;
    wB1v[k] = wvb * u1;
    wB2v[k] = wvb * u2;
  }

  size_t sb = (size_t)b * C_ * HW_;
  const float* s0p = src + sb;
  const float* s1p = s0p + HW_;
  const float* s2p = s1p + HW_;
  int ro0 = R0*W_ + bp;
  int ro1 = R1*W_ + bp;

  // ---- 6 divergent dwordx4 gathers serve BOTH pixels (3 addr/px). ----
  v4f G00 = load4(s0p + ro0);
  v4f G01 = load4(s0p + ro1);
  v4f G10 = load4(s1p + ro0);
  v4f G11 = load4(s1p + ro1);
  v4f G20 = load4(s2p + ro0);
  v4f G21 = load4(s2p + ro1);

  // Extra-row gathers: lane-predicated (~5-10% of lanes active -> TA cost
  // scales with active addresses, near-free). Zero-init so u2=0 lanes never
  // multiply uninitialized (possibly NaN) registers.
  v4f E0 = {0.f,0.f,0.f,0.f}, E1 = E0, E2 = E0;
  if (needE) {
    int roE = yE*W_ + bp;
    E0 = load4(s0p + roE);
    E1 = load4(s1p + roE);
    E2 = load4(s2p + roE);
  }
  __builtin_amdgcn_sched_barrier(0);

  float vA0 = dot4(wA0v, G00) + dot4(wA1v, G01);
  float vA1 = dot4(wA0v, G10) + dot4(wA1v, G11);
  float vA2 = dot4(wA0v, G20) + dot4(wA1v, G21);
  float vB0 = dot4(wB0v, G00) + dot4(wB1v, G01) + dot4(wB2v, E0);
  float vB1 = dot4(wB0v, G10) + dot4(wB1v, G11) + dot4(wB2v, E1);
  float vB2 = dot4(wB0v, G20) + dot4(wB1v, G21) + dot4(wB2v, E2);

  // Correctness fallback for pixel B (x-span >4 floats or 2-row straddle):
  // never taken on this data -> s_cbranch_execz skips; guarantees exactness.
  if (fb) {
    float a00 = wxB0*wyB0, a01 = wxB1*wyB0, a10 = wxB0*wyB1, a11 = wxB1*wyB1;
    int o00 = ycB0*W_ + xcB0, o01 = ycB0*W_ + xcB1;
    int o10 = ycB1*W_ + xcB0, o11 = ycB1*W_ + xcB1;
    vB0 = s0p[o00]*a00 + s0p[o01]*a01 + s0p[o10]*a10 + s0p[o11]*a11;
    vB1 = s1p[o00]*a00 + s1p[o01]*a01 + s1p[o10]*a10 + s1p[o11]*a11;
    vB2 = s2p[o00]*a00 + s2p[o01]*a01 + s2p[o10]*a10 + s2p[o11]*a11;
  }

  // Coalesced dwordx2 nt-stores (output never re-read; keeps src L3-resident).
  size_t op = (size_t)i * W_ + j0;
  storent2(out + sb + op,                    vA0, vB0);
  storent2(out + sb + HW_ + op,              vA1, vB1);
  storent2(out + sb + 2*(size_t)HW_ + op,    vA2, vB2);
}

extern "C" void kernel_launch(void* const* d_in, const int* in_sizes, int n_in,
                              void* d_out, int out_size, void* d_ws, size_t ws_size,
                              hipStream_t stream) {
  const float* src   = (const float*)d_in[0];
  const float* depth = (const float*)d_in[1];
  const float* pose  = (const float*)d_in[2];
  const float* intr  = (const float*)d_in[3];
  float* out = (float*)d_out;

  dim3 grid(NBLK_);
  warp_kernel<<<grid, 256, 0, stream>>>(src, depth, pose, intr, out);
}

// Round 5
// 264.801 us; speedup vs baseline: 1.0600x; 1.0600x over previous
//
#include <hip/hip_runtime.h>

#define B_ 16
#define C_ 3
#define H_ 384
#define W_ 1280
#define HW_ (H_*W_)
#define EPS_ 1e-7f

// R0-R4 ledger: dur pinned ~110us across 2.5x HBM-traffic and big VALU/sched
// changes; total VMEM instr count was the invariant (1.23M). R4's pairing cut
// VMEM but added ~50% VALU + divergence -> 150us (implementation, not theory,
// failed). This round: clean VMEM reduction. 4px/thread along x:
//   24 simple 8B gathers + 1 dwordx4 depth + 3 dwordx4 stores = 7 VMEM/px
// (was 10), zero added VALU/px, no predication. Also switches nt->regular
// stores to test the second theory: every round's floor equals
// 94.4MB WRITE / 110us = 0.86 TB/s -- possible nt-drain ceiling.
#define COLS_ 256
#define ROWS_ 4
#define PX_ 4
#define BANDS_ (W_/COLS_)              // 5
#define RTILES_ (H_/ROWS_)             // 96
#define NBLK_ (BANDS_*RTILES_*B_)      // 7680 (div by 8 -> swizzle bijective)
#define NXCD_ 8

typedef float v2f __attribute__((ext_vector_type(2)));
typedef float v4f __attribute__((ext_vector_type(4)));

// 8/16-byte loads at 4-byte alignment — gfx950 supports this in HW.
__device__ __forceinline__ v2f load2(const float* p) {
  v2f r; __builtin_memcpy(&r, p, 8); return r;
}
__device__ __forceinline__ v4f load4(const float* p) {
  v4f r; __builtin_memcpy(&r, p, 16); return r;
}

__device__ __forceinline__ void mat3mul(const float* A, const float* Bm, float* C) {
  #pragma unroll
  for (int i = 0; i < 3; i++)
    #pragma unroll
    for (int j = 0; j < 3; j++)
      C[i*3+j] = A[i*3+0]*Bm[0*3+j] + A[i*3+1]*Bm[1*3+j] + A[i*3+2]*Bm[2*3+j];
}

// M = K * R * inv(K), T = K * t for batch b.
__device__ void compute_MT(const float* __restrict__ pose,
                           const float* __restrict__ intr,
                           int b, float* M, float* T)
{
  float K[9];
  #pragma unroll
  for (int i = 0; i < 9; i++) K[i] = intr[b*9 + i];
  float aa0 = pose[b*6 + 0], aa1 = pose[b*6 + 1], aa2 = pose[b*6 + 2];
  float t0  = pose[b*6 + 3], t1  = pose[b*6 + 4], t2  = pose[b*6 + 5];

  float theta = sqrtf(aa0*aa0 + aa1*aa1 + aa2*aa2);
  float invn  = 1.0f / (theta + EPS_);
  float x = aa0*invn, y = aa1*invn, z = aa2*invn;
  float c = cosf(theta), s = sinf(theta), t = 1.0f - c;
  float R[9] = {
    t*x*x + c,   t*x*y - s*z, t*z*x + s*y,
    t*x*y + s*z, t*y*y + c,   t*y*z - s*x,
    t*z*x - s*y, t*y*z + s*x, t*z*z + c
  };

  float a = K[0], bb = K[1], cc = K[2];
  float d = K[3], e  = K[4], f  = K[5];
  float g = K[6], h  = K[7], ii = K[8];
  float A0 = e*ii - f*h, A1 = f*g - d*ii, A2 = d*h - e*g;
  float id = 1.0f / (a*A0 + bb*A1 + cc*A2);
  float iK[9] = {
    A0*id, (cc*h - bb*ii)*id, (bb*f - cc*e)*id,
    A1*id, (a*ii - cc*g)*id,  (cc*d - a*f)*id,
    A2*id, (bb*g - a*h)*id,   (a*e  - bb*d)*id
  };

  float KR[9];
  mat3mul(K, R, KR);
  mat3mul(KR, iK, M);
  T[0] = K[0]*t0 + K[1]*t1 + K[2]*t2;
  T[1] = K[3]*t0 + K[4]*t1 + K[5]*t2;
  T[2] = K[6]*t0 + K[7]*t1 + K[8]*t2;
}

__global__ __launch_bounds__(256) void warp_kernel(
    const float* __restrict__ src,
    const float* __restrict__ depth,
    const float* __restrict__ pose,
    const float* __restrict__ intr,
    float* __restrict__ out)
{
  __shared__ float sp[12];

  // XCD-aware bijective swizzle (R1: cut FETCH 284->57 MB; keep). rt decoded
  // fastest -> consecutive dispatch slots on one XCD are vertically adjacent
  // row-tiles of the same column band.
  int l = blockIdx.x;
  int w = (l & (NXCD_-1)) * (NBLK_/NXCD_) + (l >> 3);
  int rt   = w % RTILES_;
  int tmp  = w / RTILES_;
  int band = tmp % BANDS_;
  int b    = tmp / BANDS_;

  // Block tile: 256 cols x 4 rows. Thread t -> row (t>>6), 4 consecutive
  // columns starting at (t&63)*4. 16B-aligned depth load + output stores.
  int t  = threadIdx.x;
  int rr = t >> 6;
  int j0 = band * COLS_ + (t & 63) * PX_;
  int i  = rt * ROWS_ + rr;

  // Coalesced dwordx4 depth load issued before the barrier (hides under M/T).
  const float* dpp = depth + (size_t)b * HW_ + (size_t)i * W_ + j0;
  v4f dq = load4(dpp);

  if (t == 0) {
    float M[9], T[3];
    compute_MT(pose, intr, b, M, T);
    #pragma unroll
    for (int k = 0; k < 9; k++) sp[k] = M[k];
    #pragma unroll
    for (int k = 0; k < 3; k++) sp[9 + k] = T[k];
  }
  __syncthreads();
  float m00 = sp[0], m01 = sp[1], m02 = sp[2];
  float m10 = sp[3], m11 = sp[4], m12 = sp[5];
  float m20 = sp[6], m21 = sp[7], m22 = sp[8];
  float T0  = sp[9], T1  = sp[10], T2 = sp[11];

  float yf = (float)i;
  // y-only parts (row-invariant for this thread)
  float bx = m01*yf + m02;
  float by = m11*yf + m12;
  float bz = m21*yf + m22;

  size_t sb = (size_t)b * C_ * HW_;
  const float* s0p = src + sb;
  const float* s1p = s0p + HW_;
  const float* s2p = s1p + HW_;

  // ---- Per-pixel projection -> merged x-pair weights + row offsets.
  // All arrays fully unrolled -> compile-time indices -> registers (rule #20).
  float wax[PX_], way[PX_], wbx[PX_], wby[PX_];
  int rb0[PX_], rb1[PX_];
  #pragma unroll
  for (int q = 0; q < PX_; q++) {
    float xf = (float)(j0 + q);
    float d  = dq[q];
    float cz = (m20*xf + bz)*d + T2;
    float inv = 1.0f / (cz + EPS_);
    float px = ((m00*xf + bx)*d + T0) * inv;
    float py = ((m10*xf + by)*d + T1) * inv;

    float x0f = floorf(px), y0f = floorf(py);
    float fx1 = px - x0f, fx0 = 1.0f - fx1;
    float fy1 = py - y0f, fy0 = 1.0f - fy1;
    // masks folded into weights
    float wx0 = fx0 * ((x0f >= 0.0f && x0f <= (float)(W_-1)) ? 1.0f : 0.0f);
    float wx1 = fx1 * ((x0f+1.0f >= 0.0f && x0f+1.0f <= (float)(W_-1)) ? 1.0f : 0.0f);
    float wy0 = fy0 * ((y0f >= 0.0f && y0f <= (float)(H_-1)) ? 1.0f : 0.0f);
    float wy1 = fy1 * ((y0f+1.0f >= 0.0f && y0f+1.0f <= (float)(H_-1)) ? 1.0f : 0.0f);
    int xc0 = (int)fminf(fmaxf(x0f, 0.0f), (float)(W_-1));
    int xc1 = (int)fminf(fmaxf(x0f+1.0f, 0.0f), (float)(W_-1));
    int yc0 = (int)fminf(fmaxf(y0f, 0.0f), (float)(H_-1));
    int yc1 = (int)fminf(fmaxf(y0f+1.0f, 0.0f), (float)(H_-1));

    float w00 = wx0*wy0, w01 = wx1*wy0, w10 = wx0*wy1, w11 = wx1*wy1;
    // x-pair merge: base = min(xc0, W-2); xc0,xc1 in {base, base+1} always.
    int base = xc0 < (W_-2) ? xc0 : (W_-2);
    bool s0 = (xc0 == base);
    bool s1 = (xc1 == base + 1);
    wax[q] = (s0 ? w00 : 0.0f) + (s1 ? 0.0f : w01);
    way[q] = (s0 ? 0.0f : w00) + (s1 ? w01 : 0.0f);
    wbx[q] = (s0 ? w10 : 0.0f) + (s1 ? 0.0f : w11);
    wby[q] = (s0 ? 0.0f : w10) + (s1 ? w11 : 0.0f);
    rb0[q] = yc0*W_ + base;
    rb1[q] = yc1*W_ + base;
  }

  // ---- All 24 gathers issued back-to-back (24-deep MLP per wave). ----
  v2f gA0[PX_], gB0[PX_], gA1[PX_], gB1[PX_], gA2[PX_], gB2[PX_];
  #pragma unroll
  for (int q = 0; q < PX_; q++) {
    gA0[q] = load2(s0p + rb0[q]);
    gB0[q] = load2(s0p + rb1[q]);
    gA1[q] = load2(s1p + rb0[q]);
    gB1[q] = load2(s1p + rb1[q]);
    gA2[q] = load2(s2p + rb0[q]);
    gB2[q] = load2(s2p + rb1[q]);
  }
  // Fence: no load sinks below, no consumer hoists above -> all 24 in flight
  // before the first vmcnt wait (R3: moved VGPR 24->28, +3us; here the batch
  // is 2x deeper).
  __builtin_amdgcn_sched_barrier(0);

  v4f o0, o1, o2;
  #pragma unroll
  for (int q = 0; q < PX_; q++) {
    o0[q] = gA0[q].x*wax[q] + gA0[q].y*way[q] + gB0[q].x*wbx[q] + gB0[q].y*wby[q];
    o1[q] = gA1[q].x*wax[q] + gA1[q].y*way[q] + gB1[q].x*wbx[q] + gB1[q].y*wby[q];
    o2[q] = gA2[q].x*wax[q] + gA2[q].y*way[q] + gB2[q].x*wbx[q] + gB2[q].y*wby[q];
  }

  // REGULAR (cached) dwordx4 stores — tests the nt-drain-ceiling theory
  // (94.4MB/110us = 0.86 TB/s floor in every prior round). 16B-aligned,
  // fully coalesced: 1024B/wave/instr, full-line writes (no RMW fetch).
  size_t op = (size_t)i * W_ + j0;
  *(v4f*)(out + sb + op)                  = o0;
  *(v4f*)(out + sb + HW_ + op)            = o1;
  *(v4f*)(out + sb + 2*(size_t)HW_ + op)  = o2;
}

extern "C" void kernel_launch(void* const* d_in, const int* in_sizes, int n_in,
                              void* d_out, int out_size, void* d_ws, size_t ws_size,
                              hipStream_t stream) {
  const float* src   = (const float*)d_in[0];
  const float* depth = (const float*)d_in[1];
  const float* pose  = (const float*)d_in[2];
  const float* intr  = (const float*)d_in[3];
  float* out = (float*)d_out;

  dim3 grid(NBLK_);
  warp_kernel<<<grid, 256, 0, stream>>>(src, depth, pose, intr, out);
}

// Round 7
// 234.812 us; speedup vs baseline: 1.1953x; 1.1277x over previous
//
#include <hip/hip_runtime.h>
#include <hip/hip_fp16.h>

#define B_ 16
#define C_ 3
#define H_ 384
#define W_ 1280
#define HW_ (H_*W_)
#define EPS_ 1e-7f

// R0-R5 ledger: dur pinned 109-134us while HBM traffic varied 2.5x, VMEM
// instr count varied 30%, stores nt/regular, scheduling/VGPR varied.
// Invariant across the pinned rounds = scattered lane-request count
// (6 gathers/px x 64 lanes; depth is per-pixel random -> true scatter).
// Working theory: CU-shared TA/TCP processes ~1 scattered lane-request/cycle
// -> ~190k cyc/CU floor. Lever: requests/px, via data layout.
// Pass1 repacks src to interleaved RGBX-fp16 (8B/px); pass2 samples with ONE
// dwordx4 per row (both x-taps x 3 channels) -> 2 scattered requests/px.
// R6 BUG (fixed here): pass2 indexed the packed buffer at 16B/px instead of
// 8B/px (uint4* pointer arithmetic) -> read garbage (absmax 6.17). Now the
// gather address is computed in BYTES: (b*HW + y*W + base) * 8.
#define NXCD_ 8
#define NBLK2_ (B_*H_*(W_/256))        // 30720 pass2 blocks (div by 8)
#define CPX2_  (NBLK2_/NXCD_)          // 3840

typedef float v2f __attribute__((ext_vector_type(2)));

__device__ __forceinline__ v2f load2(const float* p) {
  v2f r; __builtin_memcpy(&r, p, 8); return r;
}
__device__ __forceinline__ uint4 load16u(const void* p) {
  uint4 r; __builtin_memcpy(&r, p, 16); return r;
}

__device__ __forceinline__ void mat3mul(const float* A, const float* Bm, float* C) {
  #pragma unroll
  for (int i = 0; i < 3; i++)
    #pragma unroll
    for (int j = 0; j < 3; j++)
      C[i*3+j] = A[i*3+0]*Bm[0*3+j] + A[i*3+1]*Bm[1*3+j] + A[i*3+2]*Bm[2*3+j];
}

// M = K * R * inv(K), T = K * t for batch b.
__device__ void compute_MT(const float* __restrict__ pose,
                           const float* __restrict__ intr,
                           int b, float* M, float* T)
{
  float K[9];
  #pragma unroll
  for (int i = 0; i < 9; i++) K[i] = intr[b*9 + i];
  float aa0 = pose[b*6 + 0], aa1 = pose[b*6 + 1], aa2 = pose[b*6 + 2];
  float t0  = pose[b*6 + 3], t1  = pose[b*6 + 4], t2  = pose[b*6 + 5];

  float theta = sqrtf(aa0*aa0 + aa1*aa1 + aa2*aa2);
  float invn  = 1.0f / (theta + EPS_);
  float x = aa0*invn, y = aa1*invn, z = aa2*invn;
  float c = cosf(theta), s = sinf(theta), t = 1.0f - c;
  float R[9] = {
    t*x*x + c,   t*x*y - s*z, t*z*x + s*y,
    t*x*y + s*z, t*y*y + c,   t*y*z - s*x,
    t*z*x - s*y, t*y*z + s*x, t*z*z + c
  };

  float a = K[0], bb = K[1], cc = K[2];
  float d = K[3], e  = K[4], f  = K[5];
  float g = K[6], h  = K[7], ii = K[8];
  float A0 = e*ii - f*h, A1 = f*g - d*ii, A2 = d*h - e*g;
  float id = 1.0f / (a*A0 + bb*A1 + cc*A2);
  float iK[9] = {
    A0*id, (cc*h - bb*ii)*id, (bb*f - cc*e)*id,
    A1*id, (a*ii - cc*g)*id,  (cc*d - a*f)*id,
    A2*id, (bb*g - a*h)*id,   (a*e  - bb*d)*id
  };

  float KR[9];
  mat3mul(K, R, KR);
  mat3mul(KR, iK, M);
  T[0] = K[0]*t0 + K[1]*t1 + K[2]*t2;
  T[1] = K[3]*t0 + K[4]*t1 + K[5]*t2;
  T[2] = K[6]*t0 + K[7]*t1 + K[8]*t2;
}

// ---- Pass 1: planar f32 [B][3][H][W] -> interleaved RGBX fp16 (8B/px). ----
// Pure streaming, fully coalesced: each thread converts 2 px (3x 8B reads,
// 1x 16B write). Regular stores: packed image must land in L2/L3 for pass2.
__global__ __launch_bounds__(256) void repack_kernel(
    const float* __restrict__ src, uint4* __restrict__ ws)
{
  int tg = blockIdx.x * 256 + threadIdx.x;     // pair index, exact fit
  int b  = tg / (HW_/2);
  int p  = (tg - b * (HW_/2)) * 2;
  const float* s = src + (size_t)b * 3 * HW_ + p;
  v2f c0 = load2(s);
  v2f c1 = load2(s + HW_);
  v2f c2 = load2(s + 2*HW_);
  __half2 h0 = __floats2half2_rn(c0.x, c1.x);  // px0: {c0,c1}
  __half2 h1 = __floats2half2_rn(c2.x, 0.0f);  // px0: {c2,pad}
  __half2 h2 = __floats2half2_rn(c0.y, c1.y);  // px1: {c0,c1}
  __half2 h3 = __floats2half2_rn(c2.y, 0.0f);  // px1: {c2,pad}
  uint4 o;
  o.x = *(unsigned*)&h0; o.y = *(unsigned*)&h1;
  o.z = *(unsigned*)&h2; o.w = *(unsigned*)&h3;
  ws[tg] = o;
}

// ---- Pass 2: 1 px/thread (R0 shape), XCD swizzle, 2 scattered gathers/px.
__global__ __launch_bounds__(256) void warp2_kernel(
    const uint4* __restrict__ pk,
    const float* __restrict__ depth,
    const float* __restrict__ pose,
    const float* __restrict__ intr,
    float* __restrict__ out)
{
  __shared__ float sp[12];

  // XCD-aware bijective swizzle, row fastest within each XCD chunk (R1: L2
  // locality for the sampled neighborhood; keep).
  int l = blockIdx.x;
  int w = (l & (NXCD_-1)) * CPX2_ + (l >> 3);
  int r    = w % H_;
  int tmp  = w / H_;
  int band = tmp % (W_/256);
  int b    = tmp / (W_/256);

  int j = band * 256 + threadIdx.x;
  int i = r;

  // Depth load before the barrier (hides under M/T compute).
  float d = depth[(size_t)b * HW_ + (size_t)i * W_ + j];

  if (threadIdx.x == 0) {
    float M[9], T[3];
    compute_MT(pose, intr, b, M, T);
    #pragma unroll
    for (int k = 0; k < 9; k++) sp[k] = M[k];
    #pragma unroll
    for (int k = 0; k < 3; k++) sp[9 + k] = T[k];
  }
  __syncthreads();
  float m00 = sp[0], m01 = sp[1], m02 = sp[2];
  float m10 = sp[3], m11 = sp[4], m12 = sp[5];
  float m20 = sp[6], m21 = sp[7], m22 = sp[8];
  float T0  = sp[9], T1  = sp[10], T2 = sp[11];

  float xf = (float)j, yf = (float)i;
  float cx = (m00*xf + m01*yf + m02)*d + T0;
  float cy = (m10*xf + m11*yf + m12)*d + T1;
  float cz = (m20*xf + m21*yf + m22)*d + T2;
  float inv = 1.0f / (cz + EPS_);
  float px = cx * inv;
  float py = cy * inv;

  float x0f = floorf(px), y0f = floorf(py);
  float x1f = x0f + 1.0f, y1f = y0f + 1.0f;
  float wx1 = px - x0f, wx0 = 1.0f - wx1;
  float wy1 = py - y0f, wy0 = 1.0f - wy1;

  float mx0 = (x0f >= 0.0f && x0f <= (float)(W_-1)) ? 1.0f : 0.0f;
  float mx1 = (x1f >= 0.0f && x1f <= (float)(W_-1)) ? 1.0f : 0.0f;
  float my0 = (y0f >= 0.0f && y0f <= (float)(H_-1)) ? 1.0f : 0.0f;
  float my1 = (y1f >= 0.0f && y1f <= (float)(H_-1)) ? 1.0f : 0.0f;

  int xc0 = (int)fminf(fmaxf(x0f, 0.0f), (float)(W_-1));
  int xc1 = (int)fminf(fmaxf(x1f, 0.0f), (float)(W_-1));
  int yc0 = (int)fminf(fmaxf(y0f, 0.0f), (float)(H_-1));
  int yc1 = (int)fminf(fmaxf(y1f, 0.0f), (float)(H_-1));

  float w00 = wx0*wy0*mx0*my0;
  float w01 = wx1*wy0*mx1*my0;
  float w10 = wx0*wy1*mx0*my1;
  float w11 = wx1*wy1*mx1*my1;

  // x-pair merge (proven R0 logic): base = min(xc0, W-2); both taps live in
  // {base, base+1} in all clamp cases; one 16B RGBX-fp16 load covers both
  // taps x 3 channels of a row.
  int base = xc0 < (W_-2) ? xc0 : (W_-2);
  bool s0 = (xc0 == base);
  bool s1 = (xc1 == base + 1);
  float wax = (s0 ? w00 : 0.0f) + (s1 ? 0.0f : w01);   // row0, tap@base
  float way = (s0 ? 0.0f : w00) + (s1 ? w01 : 0.0f);   // row0, tap@base+1
  float wbx = (s0 ? w10 : 0.0f) + (s1 ? 0.0f : w11);   // row1, tap@base
  float wby = (s0 ? 0.0f : w10) + (s1 ? w11 : 0.0f);   // row1, tap@base+1

  // BYTE addressing: packed image is 8 B/pixel (R6 bug was 16B/px indexing).
  const char* pkb = (const char*)pk;
  size_t offA = ((size_t)b * HW_ + (size_t)yc0 * W_ + base) * 8;
  size_t offB = ((size_t)b * HW_ + (size_t)yc1 * W_ + base) * 8;

  // The ONLY two scattered requests for this pixel (8B-aligned dwordx4).
  uint4 RA = load16u(pkb + offA);
  uint4 RB = load16u(pkb + offB);
  __builtin_amdgcn_sched_barrier(0);

  // Unpack: dwords = [tap0:{c0,c1},{c2,pad} | tap1:{c0,c1},{c2,pad}]
  float2 A0 = __half22float2(*(const __half2*)&RA.x);
  float  A2 = __low2float  (*(const __half2*)&RA.y);
  float2 A1 = __half22float2(*(const __half2*)&RA.z);
  float  A3 = __low2float  (*(const __half2*)&RA.w);
  float2 B0 = __half22float2(*(const __half2*)&RB.x);
  float  B2 = __low2float  (*(const __half2*)&RB.y);
  float2 B1 = __half22float2(*(const __half2*)&RB.z);
  float  B3 = __low2float  (*(const __half2*)&RB.w);

  float v0 = A0.x*wax + A1.x*way + B0.x*wbx + B1.x*wby;
  float v1 = A0.y*wax + A1.y*way + B0.y*wbx + B1.y*wby;
  float v2 = A2  *wax + A3  *way + B2  *wbx + B3  *wby;

  size_t sb = (size_t)b * C_ * HW_;
  size_t op = (size_t)i * W_ + j;
  __builtin_nontemporal_store(v0, &out[sb + op]);
  __builtin_nontemporal_store(v1, &out[sb + HW_ + op]);
  __builtin_nontemporal_store(v2, &out[sb + 2*(size_t)HW_ + op]);
}

// ---- Fallback (ws too small): the proven R0 baseline (108.9us). ----
__global__ __launch_bounds__(256) void warp_fb_kernel(
    const float* __restrict__ src,
    const float* __restrict__ depth,
    const float* __restrict__ pose,
    const float* __restrict__ intr,
    float* __restrict__ out)
{
  __shared__ float sp[12];
  int b = blockIdx.y;
  if (threadIdx.x == 0) {
    float M[9], T[3];
    compute_MT(pose, intr, b, M, T);
    #pragma unroll
    for (int k = 0; k < 9; k++) sp[k] = M[k];
    #pragma unroll
    for (int k = 0; k < 3; k++) sp[9 + k] = T[k];
  }
  __syncthreads();
  float m00 = sp[0], m01 = sp[1], m02 = sp[2];
  float m10 = sp[3], m11 = sp[4], m12 = sp[5];
  float m20 = sp[6], m21 = sp[7], m22 = sp[8];
  float T0  = sp[9], T1  = sp[10], T2 = sp[11];

  int p = blockIdx.x * 256 + threadIdx.x;
  int j = p % W_;
  int i = p / W_;

  float d  = depth[(size_t)b * HW_ + p];
  float xf = (float)j, yf = (float)i;
  float cx = (m00*xf + m01*yf + m02)*d + T0;
  float cy = (m10*xf + m11*yf + m12)*d + T1;
  float cz = (m20*xf + m21*yf + m22)*d + T2;
  float inv = 1.0f / (cz + EPS_);
  float px = cx * inv, py = cy * inv;

  float x0f = floorf(px), y0f = floorf(py);
  float x1f = x0f + 1.0f, y1f = y0f + 1.0f;
  float wx1 = px - x0f, wx0 = 1.0f - wx1;
  float wy1 = py - y0f, wy0 = 1.0f - wy1;
  float mx0 = (x0f >= 0.0f && x0f <= (float)(W_-1)) ? 1.0f : 0.0f;
  float mx1 = (x1f >= 0.0f && x1f <= (float)(W_-1)) ? 1.0f : 0.0f;
  float my0 = (y0f >= 0.0f && y0f <= (float)(H_-1)) ? 1.0f : 0.0f;
  float my1 = (y1f >= 0.0f && y1f <= (float)(H_-1)) ? 1.0f : 0.0f;
  int xc0 = (int)fminf(fmaxf(x0f, 0.0f), (float)(W_-1));
  int xc1 = (int)fminf(fmaxf(x1f, 0.0f), (float)(W_-1));
  int yc0 = (int)fminf(fmaxf(y0f, 0.0f), (float)(H_-1));
  int yc1 = (int)fminf(fmaxf(y1f, 0.0f), (float)(H_-1));
  float w00 = wx0*wy0*mx0*my0;
  float w01 = wx1*wy0*mx1*my0;
  float w10 = wx0*wy1*mx0*my1;
  float w11 = wx1*wy1*mx1*my1;
  int base = xc0 < (W_-2) ? xc0 : (W_-2);
  bool s0 = (xc0 == base);
  bool s1 = (xc1 == base + 1);
  float wax = (s0 ? w00 : 0.0f) + (s1 ? 0.0f : w01);
  float way = (s0 ? 0.0f : w00) + (s1 ? w01 : 0.0f);
  float wbx = (s0 ? w10 : 0.0f) + (s1 ? 0.0f : w11);
  float wby = (s0 ? 0.0f : w10) + (s1 ? w11 : 0.0f);
  int rb0 = yc0*W_ + base;
  int rb1 = yc1*W_ + base;

  size_t sb = (size_t)b * C_ * HW_;
  const float* s0p = src + sb;
  const float* s1p = s0p + HW_;
  const float* s2p = s1p + HW_;
  v2f a0 = load2(s0p + rb0);
  v2f b0 = load2(s0p + rb1);
  v2f a1 = load2(s1p + rb0);
  v2f b1 = load2(s1p + rb1);
  v2f a2 = load2(s2p + rb0);
  v2f b2 = load2(s2p + rb1);
  float v0 = a0.x*wax + a0.y*way + b0.x*wbx + b0.y*wby;
  float v1 = a1.x*wax + a1.y*way + b1.x*wbx + b1.y*wby;
  float v2 = a2.x*wax + a2.y*way + b2.x*wbx + b2.y*wby;
  size_t op = (size_t)p;
  __builtin_nontemporal_store(v0, &out[sb + op]);
  __builtin_nontemporal_store(v1, &out[sb + HW_ + op]);
  __builtin_nontemporal_store(v2, &out[sb + 2*(size_t)HW_ + op]);
}

extern "C" void kernel_launch(void* const* d_in, const int* in_sizes, int n_in,
                              void* d_out, int out_size, void* d_ws, size_t ws_size,
                              hipStream_t stream) {
  const float* src   = (const float*)d_in[0];
  const float* depth = (const float*)d_in[1];
  const float* pose  = (const float*)d_in[2];
  const float* intr  = (const float*)d_in[3];
  float* out = (float*)d_out;

  const size_t need = (size_t)B_ * HW_ * 8;   // 62.9 MB packed RGBX-fp16
  if (d_ws != nullptr && ws_size >= need) {
    uint4* ws = (uint4*)d_ws;
    repack_kernel<<<dim3(B_*HW_/2/256), 256, 0, stream>>>(src, ws);
    warp2_kernel<<<dim3(NBLK2_), 256, 0, stream>>>(ws, depth, pose, intr, out);
  } else {
    dim3 grid(HW_ / 256, B_);
    warp_fb_kernel<<<grid, 256, 0, stream>>>(src, depth, pose, intr, out);
  }
}

// Round 8
// 231.187 us; speedup vs baseline: 1.2141x; 1.0157x over previous
//
#include <hip/hip_runtime.h>
#include <hip/hip_fp16.h>

#define B_ 16
#define C_ 3
#define H_ 384
#define W_ 1280
#define HW_ (H_*W_)
#define EPS_ 1e-7f

// LEDGER: R0-R5 dur pinned 109-134us across traffic/sched/VGPR changes ->
// bottleneck = scattered lane-request rate at the CU TA/TCP. R7 proved it:
// RGBX-fp16 repack (8B/px) + ONE dwordx4 per row-tap-pair = 2 scattered
// requests/px -> 67.5us sampler (was 109). This round: cut remaining VMEM
// instruction overhead. repack v2: 4px/thread, nt dwordx4 loads (src dead
// after pass1). warp2 v3: 2px/thread -> depth dwordx2, stores dwordx2,
// 8 VMEM instr/2px (was 12); scatter/px unchanged (structural).
#define NXCD_ 8

// warp2 v3 tiling: 256 cols x 2 rows per block, 2px/thread.
#define BANDS_ (W_/256)                 // 5
#define RTILES_ (H_/2)                  // 192
#define NBLK3_ (BANDS_*RTILES_*B_)      // 15360 (div 8 -> swizzle bijective)
#define CPX3_  (NBLK3_/NXCD_)           // 1920

typedef float v2f __attribute__((ext_vector_type(2)));
typedef float v4f __attribute__((ext_vector_type(4)));

__device__ __forceinline__ v2f load2(const float* p) {
  v2f r; __builtin_memcpy(&r, p, 8); return r;
}
__device__ __forceinline__ uint4 load16u(const void* p) {
  uint4 r; __builtin_memcpy(&r, p, 16); return r;
}
__device__ __forceinline__ v4f ntload4(const float* p) {
  return __builtin_nontemporal_load((const v4f*)p);   // 16B-aligned
}
__device__ __forceinline__ void storent2(float* p, float a, float b) {
  v2f r; r.x = a; r.y = b;
  __builtin_nontemporal_store(r, (v2f*)p);            // 8B-aligned (even col)
}
__device__ __forceinline__ unsigned pack2(float a, float b) {
  __half2 h = __floats2half2_rn(a, b);
  unsigned u; __builtin_memcpy(&u, &h, 4); return u;
}

__device__ __forceinline__ void mat3mul(const float* A, const float* Bm, float* C) {
  #pragma unroll
  for (int i = 0; i < 3; i++)
    #pragma unroll
    for (int j = 0; j < 3; j++)
      C[i*3+j] = A[i*3+0]*Bm[0*3+j] + A[i*3+1]*Bm[1*3+j] + A[i*3+2]*Bm[2*3+j];
}

// M = K * R * inv(K), T = K * t for batch b.
__device__ void compute_MT(const float* __restrict__ pose,
                           const float* __restrict__ intr,
                           int b, float* M, float* T)
{
  float K[9];
  #pragma unroll
  for (int i = 0; i < 9; i++) K[i] = intr[b*9 + i];
  float aa0 = pose[b*6 + 0], aa1 = pose[b*6 + 1], aa2 = pose[b*6 + 2];
  float t0  = pose[b*6 + 3], t1  = pose[b*6 + 4], t2  = pose[b*6 + 5];

  float theta = sqrtf(aa0*aa0 + aa1*aa1 + aa2*aa2);
  float invn  = 1.0f / (theta + EPS_);
  float x = aa0*invn, y = aa1*invn, z = aa2*invn;
  float c = cosf(theta), s = sinf(theta), t = 1.0f - c;
  float R[9] = {
    t*x*x + c,   t*x*y - s*z, t*z*x + s*y,
    t*x*y + s*z, t*y*y + c,   t*y*z - s*x,
    t*z*x - s*y, t*y*z + s*x, t*z*z + c
  };

  float a = K[0], bb = K[1], cc = K[2];
  float d = K[3], e  = K[4], f  = K[5];
  float g = K[6], h  = K[7], ii = K[8];
  float A0 = e*ii - f*h, A1 = f*g - d*ii, A2 = d*h - e*g;
  float id = 1.0f / (a*A0 + bb*A1 + cc*A2);
  float iK[9] = {
    A0*id, (cc*h - bb*ii)*id, (bb*f - cc*e)*id,
    A1*id, (a*ii - cc*g)*id,  (cc*d - a*f)*id,
    A2*id, (bb*g - a*h)*id,   (a*e  - bb*d)*id
  };

  float KR[9];
  mat3mul(K, R, KR);
  mat3mul(KR, iK, M);
  T[0] = K[0]*t0 + K[1]*t1 + K[2]*t2;
  T[1] = K[3]*t0 + K[4]*t1 + K[5]*t2;
  T[2] = K[6]*t0 + K[7]*t1 + K[8]*t2;
}

// ---- Pass 1 v2: planar f32 -> interleaved RGBX fp16 (8B/px), 4 px/thread.
// nt loads: src is never read again -> keep it from polluting L2/L3 (which
// must hold the packed buffer + output stream). 5 VMEM instr / 4 px.
__global__ __launch_bounds__(256) void repack_kernel(
    const float* __restrict__ src, uint4* __restrict__ ws)
{
  int tg = blockIdx.x * 256 + threadIdx.x;     // quad index, exact fit
  int b  = tg / (HW_/4);
  int p  = (tg - b * (HW_/4)) * 4;
  const float* s = src + (size_t)b * 3 * HW_ + p;
  v4f c0 = ntload4(s);
  v4f c1 = ntload4(s + HW_);
  v4f c2 = ntload4(s + 2*HW_);
  uint4 o0, o1;
  o0.x = pack2(c0.x, c1.x); o0.y = pack2(c2.x, 0.0f);   // px0
  o0.z = pack2(c0.y, c1.y); o0.w = pack2(c2.y, 0.0f);   // px1
  o1.x = pack2(c0.z, c1.z); o1.y = pack2(c2.z, 0.0f);   // px2
  o1.z = pack2(c0.w, c1.w); o1.w = pack2(c2.w, 0.0f);   // px3
  ws[(size_t)tg*2]     = o0;   // regular stores: packed image must be cached
  ws[(size_t)tg*2 + 1] = o1;
}

// ---- Pass 2 v3: 2 px/thread (x-pair), 256x2 tile, XCD swizzle.
// Per 2px: 4 scattered dwordx4 gathers + 1 dwordx2 depth + 3 dwordx2 stores
// = 8 VMEM instr (R7 was 12). Scatter/px stays 2 (structural for bilinear).
__global__ __launch_bounds__(256) void warp2_kernel(
    const uint4* __restrict__ pk,
    const float* __restrict__ depth,
    const float* __restrict__ pose,
    const float* __restrict__ intr,
    float* __restrict__ out)
{
  __shared__ float sp[12];

  // XCD-aware bijective swizzle, row-tile fastest within each XCD chunk.
  int l = blockIdx.x;
  int w = (l & (NXCD_-1)) * CPX3_ + (l >> 3);
  int rt   = w % RTILES_;
  int tmp  = w / RTILES_;
  int band = tmp % BANDS_;
  int b    = tmp / BANDS_;

  int t  = threadIdx.x;
  int rr = t >> 7;                  // 0/1: row within the 2-row tile
  int cp = t & 127;                 // column pair
  int j0 = band * 256 + 2*cp;       // even column: pixels A=j0, B=j0+1
  int i  = rt * 2 + rr;

  // Coalesced dwordx2 depth load before the barrier (hides under M/T).
  v2f dq = load2(depth + (size_t)b * HW_ + (size_t)i * W_ + j0);

  if (t == 0) {
    float M[9], T[3];
    compute_MT(pose, intr, b, M, T);
    #pragma unroll
    for (int k = 0; k < 9; k++) sp[k] = M[k];
    #pragma unroll
    for (int k = 0; k < 3; k++) sp[9 + k] = T[k];
  }
  __syncthreads();
  float m00 = sp[0], m01 = sp[1], m02 = sp[2];
  float m10 = sp[3], m11 = sp[4], m12 = sp[5];
  float m20 = sp[6], m21 = sp[7], m22 = sp[8];
  float T0  = sp[9], T1  = sp[10], T2 = sp[11];

  float yf = (float)i;
  float bx = m01*yf + m02;
  float by = m11*yf + m12;
  float bz = m21*yf + m22;

  const char* pkb = (const char*)pk;
  size_t pb = (size_t)b * HW_;

  // ---- Pixel A projection -> weights + byte offsets ----
  float xfA = (float)j0;
  float dA  = dq.x;
  float czA = (m20*xfA + bz)*dA + T2;
  float ivA = 1.0f / (czA + EPS_);
  float pxA = ((m00*xfA + bx)*dA + T0) * ivA;
  float pyA = ((m10*xfA + by)*dA + T1) * ivA;
  float x0A = floorf(pxA), y0A = floorf(pyA);
  float fx1A = pxA - x0A, fx0A = 1.0f - fx1A;
  float fy1A = pyA - y0A, fy0A = 1.0f - fy1A;
  float wx0A = fx0A * ((x0A >= 0.0f && x0A <= (float)(W_-1)) ? 1.0f : 0.0f);
  float wx1A = fx1A * ((x0A+1.0f >= 0.0f && x0A+1.0f <= (float)(W_-1)) ? 1.0f : 0.0f);
  float wy0A = fy0A * ((y0A >= 0.0f && y0A <= (float)(H_-1)) ? 1.0f : 0.0f);
  float wy1A = fy1A * ((y0A+1.0f >= 0.0f && y0A+1.0f <= (float)(H_-1)) ? 1.0f : 0.0f);
  int xc0A = (int)fminf(fmaxf(x0A, 0.0f), (float)(W_-1));
  int xc1A = (int)fminf(fmaxf(x0A+1.0f, 0.0f), (float)(W_-1));
  int yc0A = (int)fminf(fmaxf(y0A, 0.0f), (float)(H_-1));
  int yc1A = (int)fminf(fmaxf(y0A+1.0f, 0.0f), (float)(H_-1));
  float w00A = wx0A*wy0A, w01A = wx1A*wy0A, w10A = wx0A*wy1A, w11A = wx1A*wy1A;
  int baseA = xc0A < (W_-2) ? xc0A : (W_-2);
  bool s0A = (xc0A == baseA), s1A = (xc1A == baseA + 1);
  float waxA = (s0A ? w00A : 0.0f) + (s1A ? 0.0f : w01A);
  float wayA = (s0A ? 0.0f : w00A) + (s1A ? w01A : 0.0f);
  float wbxA = (s0A ? w10A : 0.0f) + (s1A ? 0.0f : w11A);
  float wbyA = (s0A ? 0.0f : w10A) + (s1A ? w11A : 0.0f);
  size_t offA0 = (pb + (size_t)yc0A * W_ + baseA) * 8;
  size_t offA1 = (pb + (size_t)yc1A * W_ + baseA) * 8;

  // ---- Pixel B projection ----
  float xfB = (float)(j0 + 1);
  float dB  = dq.y;
  float czB = (m20*xfB + bz)*dB + T2;
  float ivB = 1.0f / (czB + EPS_);
  float pxB = ((m00*xfB + bx)*dB + T0) * ivB;
  float pyB = ((m10*xfB + by)*dB + T1) * ivB;
  float x0B = floorf(pxB), y0B = floorf(pyB);
  float fx1B = pxB - x0B, fx0B = 1.0f - fx1B;
  float fy1B = pyB - y0B, fy0B = 1.0f - fy1B;
  float wx0B = fx0B * ((x0B >= 0.0f && x0B <= (float)(W_-1)) ? 1.0f : 0.0f);
  float wx1B = fx1B * ((x0B+1.0f >= 0.0f && x0B+1.0f <= (float)(W_-1)) ? 1.0f : 0.0f);
  float wy0B = fy0B * ((y0B >= 0.0f && y0B <= (float)(H_-1)) ? 1.0f : 0.0f);
  float wy1B = fy1B * ((y0B+1.0f >= 0.0f && y0B+1.0f <= (float)(H_-1)) ? 1.0f : 0.0f);
  int xc0B = (int)fminf(fmaxf(x0B, 0.0f), (float)(W_-1));
  int xc1B = (int)fminf(fmaxf(x0B+1.0f, 0.0f), (float)(W_-1));
  int yc0B = (int)fminf(fmaxf(y0B, 0.0f), (float)(H_-1));
  int yc1B = (int)fminf(fmaxf(y0B+1.0f, 0.0f), (float)(H_-1));
  float w00B = wx0B*wy0B, w01B = wx1B*wy0B, w10B = wx0B*wy1B, w11B = wx1B*wy1B;
  int baseB = xc0B < (W_-2) ? xc0B : (W_-2);
  bool s0B = (xc0B == baseB), s1B = (xc1B == baseB + 1);
  float waxB = (s0B ? w00B : 0.0f) + (s1B ? 0.0f : w01B);
  float wayB = (s0B ? 0.0f : w00B) + (s1B ? w01B : 0.0f);
  float wbxB = (s0B ? w10B : 0.0f) + (s1B ? 0.0f : w11B);
  float wbyB = (s0B ? 0.0f : w10B) + (s1B ? w11B : 0.0f);
  size_t offB0 = (pb + (size_t)yc0B * W_ + baseB) * 8;
  size_t offB1 = (pb + (size_t)yc1B * W_ + baseB) * 8;

  // ---- 4 scattered gathers back-to-back (8B-aligned dwordx4) ----
  uint4 RA0 = load16u(pkb + offA0);
  uint4 RA1 = load16u(pkb + offA1);
  uint4 RB0 = load16u(pkb + offB0);
  uint4 RB1 = load16u(pkb + offB1);
  __builtin_amdgcn_sched_barrier(0);

  // Unpack: dwords = [tap0:{c0,c1},{c2,pad} | tap1:{c0,c1},{c2,pad}]
  float2 A00 = __half22float2(*(const __half2*)&RA0.x);
  float  A02 = __low2float  (*(const __half2*)&RA0.y);
  float2 A01 = __half22float2(*(const __half2*)&RA0.z);
  float  A03 = __low2float  (*(const __half2*)&RA0.w);
  float2 A10 = __half22float2(*(const __half2*)&RA1.x);
  float  A12 = __low2float  (*(const __half2*)&RA1.y);
  float2 A11 = __half22float2(*(const __half2*)&RA1.z);
  float  A13 = __low2float  (*(const __half2*)&RA1.w);
  float vA0 = A00.x*waxA + A01.x*wayA + A10.x*wbxA + A11.x*wbyA;
  float vA1 = A00.y*waxA + A01.y*wayA + A10.y*wbxA + A11.y*wbyA;
  float vA2 = A02  *waxA + A03  *wayA + A12  *wbxA + A13  *wbyA;

  float2 B00 = __half22float2(*(const __half2*)&RB0.x);
  float  B02 = __low2float  (*(const __half2*)&RB0.y);
  float2 B01 = __half22float2(*(const __half2*)&RB0.z);
  float  B03 = __low2float  (*(const __half2*)&RB0.w);
  float2 B10 = __half22float2(*(const __half2*)&RB1.x);
  float  B12 = __low2float  (*(const __half2*)&RB1.y);
  float2 B11 = __half22float2(*(const __half2*)&RB1.z);
  float  B13 = __low2float  (*(const __half2*)&RB1.w);
  float vB0 = B00.x*waxB + B01.x*wayB + B10.x*wbxB + B11.x*wbyB;
  float vB1 = B00.y*waxB + B01.y*wayB + B10.y*wbxB + B11.y*wbyB;
  float vB2 = B02  *waxB + B03  *wayB + B12  *wbxB + B13  *wbyB;

  // 3 coalesced dwordx2 nt-stores (even j0 -> 8B-aligned).
  size_t sb = (size_t)b * C_ * HW_;
  size_t op = (size_t)i * W_ + j0;
  storent2(out + sb + op,                   vA0, vB0);
  storent2(out + sb + HW_ + op,             vA1, vB1);
  storent2(out + sb + 2*(size_t)HW_ + op,   vA2, vB2);
}

// ---- Fallback (ws too small): the proven R0 baseline (108.9us). ----
__global__ __launch_bounds__(256) void warp_fb_kernel(
    const float* __restrict__ src,
    const float* __restrict__ depth,
    const float* __restrict__ pose,
    const float* __restrict__ intr,
    float* __restrict__ out)
{
  __shared__ float sp[12];
  int b = blockIdx.y;
  if (threadIdx.x == 0) {
    float M[9], T[3];
    compute_MT(pose, intr, b, M, T);
    #pragma unroll
    for (int k = 0; k < 9; k++) sp[k] = M[k];
    #pragma unroll
    for (int k = 0; k < 3; k++) sp[9 + k] = T[k];
  }
  __syncthreads();
  float m00 = sp[0], m01 = sp[1], m02 = sp[2];
  float m10 = sp[3], m11 = sp[4], m12 = sp[5];
  float m20 = sp[6], m21 = sp[7], m22 = sp[8];
  float T0  = sp[9], T1  = sp[10], T2 = sp[11];

  int p = blockIdx.x * 256 + threadIdx.x;
  int j = p % W_;
  int i = p / W_;

  float d  = depth[(size_t)b * HW_ + p];
  float xf = (float)j, yf = (float)i;
  float cx = (m00*xf + m01*yf + m02)*d + T0;
  float cy = (m10*xf + m11*yf + m12)*d + T1;
  float cz = (m20*xf + m21*yf + m22)*d + T2;
  float inv = 1.0f / (cz + EPS_);
  float px = cx * inv, py = cy * inv;

  float x0f = floorf(px), y0f = floorf(py);
  float x1f = x0f + 1.0f, y1f = y0f + 1.0f;
  float wx1 = px - x0f, wx0 = 1.0f - wx1;
  float wy1 = py - y0f, wy0 = 1.0f - wy1;
  float mx0 = (x0f >= 0.0f && x0f <= (float)(W_-1)) ? 1.0f : 0.0f;
  float mx1 = (x1f >= 0.0f && x1f <= (float)(W_-1)) ? 1.0f : 0.0f;
  float my0 = (y0f >= 0.0f && y0f <= (float)(H_-1)) ? 1.0f : 0.0f;
  float my1 = (y1f >= 0.0f && y1f <= (float)(H_-1)) ? 1.0f : 0.0f;
  int xc0 = (int)fminf(fmaxf(x0f, 0.0f), (float)(W_-1));
  int xc1 = (int)fminf(fmaxf(x1f, 0.0f), (float)(W_-1));
  int yc0 = (int)fminf(fmaxf(y0f, 0.0f), (float)(H_-1));
  int yc1 = (int)fminf(fmaxf(y1f, 0.0f), (float)(H_-1));
  float w00 = wx0*wy0*mx0*my0;
  float w01 = wx1*wy0*mx1*my0;
  float w10 = wx0*wy1*mx0*my1;
  float w11 = wx1*wy1*mx1*my1;
  int base = xc0 < (W_-2) ? xc0 : (W_-2);
  bool s0 = (xc0 == base);
  bool s1 = (xc1 == base + 1);
  float wax = (s0 ? w00 : 0.0f) + (s1 ? 0.0f : w01);
  float way = (s0 ? 0.0f : w00) + (s1 ? w01 : 0.0f);
  float wbx = (s0 ? w10 : 0.0f) + (s1 ? 0.0f : w11);
  float wby = (s0 ? 0.0f : w10) + (s1 ? w11 : 0.0f);
  int rb0 = yc0*W_ + base;
  int rb1 = yc1*W_ + base;

  size_t sb = (size_t)b * C_ * HW_;
  const float* s0p = src + sb;
  const float* s1p = s0p + HW_;
  const float* s2p = s1p + HW_;
  v2f a0 = load2(s0p + rb0);
  v2f b0 = load2(s0p + rb1);
  v2f a1 = load2(s1p + rb0);
  v2f b1 = load2(s1p + rb1);
  v2f a2 = load2(s2p + rb0);
  v2f b2 = load2(s2p + rb1);
  float v0 = a0.x*wax + a0.y*way + b0.x*wbx + b0.y*wby;
  float v1 = a1.x*wax + a1.y*way + b1.x*wbx + b1.y*wby;
  float v2 = a2.x*wax + a2.y*way + b2.x*wbx + b2.y*wby;
  size_t op = (size_t)p;
  __builtin_nontemporal_store(v0, &out[sb + op]);
  __builtin_nontemporal_store(v1, &out[sb + HW_ + op]);
  __builtin_nontemporal_store(v2, &out[sb + 2*(size_t)HW_ + op]);
}

extern "C" void kernel_launch(void* const* d_in, const int* in_sizes, int n_in,
                              void* d_out, int out_size, void* d_ws, size_t ws_size,
                              hipStream_t stream) {
  const float* src   = (const float*)d_in[0];
  const float* depth = (const float*)d_in[1];
  const float* pose  = (const float*)d_in[2];
  const float* intr  = (const float*)d_in[3];
  float* out = (float*)d_out;

  const size_t need = (size_t)B_ * HW_ * 8;   // 62.9 MB packed RGBX-fp16
  if (d_ws != nullptr && ws_size >= need) {
    uint4* ws = (uint4*)d_ws;
    repack_kernel<<<dim3(B_*HW_/4/256), 256, 0, stream>>>(src, ws);
    warp2_kernel<<<dim3(NBLK3_), 256, 0, stream>>>(ws, depth, pose, intr, out);
  } else {
    dim3 grid(HW_ / 256, B_);
    warp_fb_kernel<<<grid, 256, 0, stream>>>(src, depth, pose, intr, out);
  }
}